// Round 1
// baseline (1945.246 us; speedup 1.0000x reference)
//
#include <hip/hip_runtime.h>

// SIRLayer inference, MI355X. All float tensors fp32, coors int32.
// K1a: rel-MLP gate -> gated feats G (stored in d_out).
// K1b: p0 = relu(G @ vfe_w0 *g +b)  (in-place on d_out, rows block-private)
//      + filtered scatter-max into voxel buffer (d_ws).
// K2 : p1 = relu(concat(p0, v0[coor]) @ vfe_w1 *g +b) + shortcut, in-place.
//
// K1b/K2 GEMM layout: 256 threads / 256 points per block.
//   thread t -> ps = t>>2 (point slot), cg = t&3 (16-channel group)
//   owns points {base+ps+64*i, i=0..3} x channels [cg*16, cg*16+16)
//   => acc[4][16] regs; 16 LDS b128 weight reads per 4-k step amortized
//      over 256 independent FMAs; activation float4 loads double-buffered.

#define VVOX 65536

// ---------------------------------------------------------------------------
// K1a: gate MLP. G[pt][k] = feats[k] * relu(h . w1[:,k] + b1), h = relu(fc@w0)
// ---------------------------------------------------------------------------
__global__ void __launch_bounds__(256)
sir_k1a(const float* __restrict__ xyz,
        const float* __restrict__ pfeat,
        const float* __restrict__ fclu,
        const float* __restrict__ rw0,
        const float* __restrict__ rg0,
        const float* __restrict__ rb0,
        const float* __restrict__ rw1,
        const float* __restrict__ rg1,
        const float* __restrict__ rb1,
        float* __restrict__ G,       // = d_out, [N,64]
        int npts)
{
    __shared__ float s_w0[48];    // rel_w0 [i*16+j] * g0[j]
    __shared__ float s_b0[16];
    __shared__ float s_w1t[1024]; // [k*16+j] = w1[j][k]*g1[k]
    __shared__ float s_b1[64];

    const int t = threadIdx.x;
    if (t < 48) s_w0[t] = rw0[t] * rg0[t & 15];
    if (t < 16) s_b0[t] = rb0[t];
    for (int i = t; i < 1024; i += 256) {
        int k = i >> 4, j = i & 15;
        s_w1t[i] = rw1[j * 64 + k] * rg1[k];
    }
    if (t < 64) s_b1[t] = rb1[t];
    __syncthreads();

    const int pt = blockIdx.x * 256 + t;
    if (pt >= npts) return;

    const float* cr = fclu + (size_t)pt * 3;
    const float c0 = cr[0], c1 = cr[1], c2 = cr[2];
    float h[16];
    #pragma unroll
    for (int j = 0; j < 16; ++j) {
        float v = s_b0[j];
        v = fmaf(c0, s_w0[j], v);
        v = fmaf(c1, s_w0[16 + j], v);
        v = fmaf(c2, s_w0[32 + j], v);
        h[j] = fmaxf(v, 0.f);
    }

    const float* xr = xyz + (size_t)pt * 3;
    const float* fr = pfeat + (size_t)pt * 61;
    float4* Grow = reinterpret_cast<float4*>(G + (size_t)pt * 64);

    #pragma unroll 4
    for (int k4 = 0; k4 < 16; ++k4) {
        float u[4];
        #pragma unroll
        for (int kk = 0; kk < 4; ++kk) {
            const int k = k4 * 4 + kk;
            const float* w1k = s_w1t + k * 16;
            float g0 = s_b1[k], g1 = 0.f, g2 = 0.f, g3 = 0.f;
            #pragma unroll
            for (int j = 0; j < 4; ++j) {
                g0 = fmaf(h[j],      w1k[j],      g0);
                g1 = fmaf(h[4 + j],  w1k[4 + j],  g1);
                g2 = fmaf(h[8 + j],  w1k[8 + j],  g2);
                g3 = fmaf(h[12 + j], w1k[12 + j], g3);
            }
            const float g = fmaxf((g0 + g1) + (g2 + g3), 0.f);
            const float fk = (k < 3) ? xr[k] : fr[k - 3];
            u[kk] = fk * g;
        }
        float4 uu;
        uu.x = u[0]; uu.y = u[1]; uu.z = u[2]; uu.w = u[3];
        Grow[k4] = uu;
    }
}

// ---------------------------------------------------------------------------
// K1b: p0 = relu(G @ w0s + b0s), scatter-max into vmax. In-place on G rows.
// ---------------------------------------------------------------------------
__global__ void __launch_bounds__(256)
sir_k1b(const float* __restrict__ G,       // = d_out
        const int* __restrict__ coors,
        const float* __restrict__ vw0,
        const float* __restrict__ vg0,
        const float* __restrict__ vb0,
        unsigned int* __restrict__ vmax,   // [V*64] fp32 bits, pre-zeroed
        float* __restrict__ p0out,         // = d_out (in-place)
        int npts)
{
    __shared__ float s_w[4096];  // vw0[k*64+c] * vg0[c]
    __shared__ float s_b[64];
    const int t = threadIdx.x;
    for (int i = t; i < 4096; i += 256) s_w[i] = vw0[i] * vg0[i & 63];
    if (t < 64) s_b[t] = vb0[t];
    __syncthreads();

    const int cg = t & 3;
    const int ps = t >> 2;
    const int base = blockIdx.x * 256;

    int p[4]; bool ok[4];
    const float4* Gp[4];
    #pragma unroll
    for (int i = 0; i < 4; ++i) {
        p[i] = base + ps + 64 * i;
        ok[i] = p[i] < npts;
        const int pc = ok[i] ? p[i] : 0;
        Gp[i] = reinterpret_cast<const float4*>(G + (size_t)pc * 64);
    }

    float acc[4][16];
    #pragma unroll
    for (int i = 0; i < 4; ++i)
        #pragma unroll
        for (int c = 0; c < 16; ++c) acc[i][c] = s_b[cg * 16 + c];

    float4 gv[4], gvn[4];
    #pragma unroll
    for (int i = 0; i < 4; ++i) gv[i] = Gp[i][0];

    for (int k4 = 0; k4 < 16; ++k4) {
        const int k4n = (k4 + 1) & 15;           // wraps; redundant last load
        #pragma unroll
        for (int i = 0; i < 4; ++i) gvn[i] = Gp[i][k4n];
        const float* wb = s_w + k4 * 256 + cg * 16;
        #pragma unroll
        for (int kk = 0; kk < 4; ++kk) {
            const float* wr = wb + kk * 64;
            #pragma unroll
            for (int i = 0; i < 4; ++i) {
                const float ga[4] = { gv[i].x, gv[i].y, gv[i].z, gv[i].w };
                const float gk = ga[kk];
                #pragma unroll
                for (int c = 0; c < 16; ++c)
                    acc[i][c] = fmaf(gk, wr[c], acc[i][c]);
            }
        }
        #pragma unroll
        for (int i = 0; i < 4; ++i) gv[i] = gvn[i];
    }

    // all reads of this block's G rows complete before any in-place overwrite
    __syncthreads();

    #pragma unroll
    for (int i = 0; i < 4; ++i) {
        if (!ok[i]) continue;
        const int vox = coors[p[i]];
        unsigned int* vrow = vmax + (size_t)vox * 64 + cg * 16;
        const uint4* vrow4 = reinterpret_cast<const uint4*>(vrow);
        float4* orow = reinterpret_cast<float4*>(p0out + (size_t)p[i] * 64 + cg * 16);
        #pragma unroll
        for (int q = 0; q < 4; ++q) {
            // filtered scatter-max: vmax cells monotone non-decreasing, >=0;
            // stale read <= current, so skipping when p <= stale is safe.
            const uint4 cur = vrow4[q];
            float4 u;
            u.x = fmaxf(acc[i][q * 4 + 0], 0.f);
            u.y = fmaxf(acc[i][q * 4 + 1], 0.f);
            u.z = fmaxf(acc[i][q * 4 + 2], 0.f);
            u.w = fmaxf(acc[i][q * 4 + 3], 0.f);
            orow[q] = u;
            if (__float_as_uint(u.x) > cur.x) atomicMax(vrow + q * 4 + 0, __float_as_uint(u.x));
            if (__float_as_uint(u.y) > cur.y) atomicMax(vrow + q * 4 + 1, __float_as_uint(u.y));
            if (__float_as_uint(u.z) > cur.z) atomicMax(vrow + q * 4 + 2, __float_as_uint(u.z));
            if (__float_as_uint(u.w) > cur.w) atomicMax(vrow + q * 4 + 3, __float_as_uint(u.w));
        }
    }
}

// ---------------------------------------------------------------------------
// K2: p1 = relu(concat(p0, v0[coor]) @ w1s + b1s) + concat(xyz, pfeat)
// ---------------------------------------------------------------------------
__global__ void __launch_bounds__(256)
sir_k2(const float* __restrict__ xyz,
       const float* __restrict__ pfeat,
       const int* __restrict__ coors,
       const float* __restrict__ vw1,
       const float* __restrict__ vg1,
       const float* __restrict__ vb1,
       const float* __restrict__ vmaxf,   // [V*64] fp32
       float* __restrict__ io,            // d_out: in p0, out result
       int npts)
{
    __shared__ float s_w[8192];  // vw1[k*64+c] * vg1[c], k<128
    __shared__ float s_b[64];
    const int t = threadIdx.x;
    for (int i = t; i < 8192; i += 256) s_w[i] = vw1[i] * vg1[i & 63];
    if (t < 64) s_b[t] = vb1[t];
    __syncthreads();

    const int cg = t & 3;
    const int ps = t >> 2;
    const int base = blockIdx.x * 256;

    int p[4]; bool ok[4];
    const float4* prow[4];
    const float4* vrow[4];
    #pragma unroll
    for (int i = 0; i < 4; ++i) {
        p[i] = base + ps + 64 * i;
        ok[i] = p[i] < npts;
        const int pc = ok[i] ? p[i] : 0;
        prow[i] = reinterpret_cast<const float4*>(io + (size_t)pc * 64);
        const int vox = coors[pc];
        vrow[i] = reinterpret_cast<const float4*>(vmaxf + (size_t)vox * 64);
    }

    float acc[4][16];
    #pragma unroll
    for (int i = 0; i < 4; ++i)
        #pragma unroll
        for (int c = 0; c < 16; ++c) acc[i][c] = s_b[cg * 16 + c];

    float4 gv[4], gvn[4];

    // ---- part 1: p0 rows @ w[0:64] ----
    #pragma unroll
    for (int i = 0; i < 4; ++i) gv[i] = prow[i][0];
    for (int k4 = 0; k4 < 16; ++k4) {
        const int k4n = (k4 + 1) & 15;
        #pragma unroll
        for (int i = 0; i < 4; ++i) gvn[i] = prow[i][k4n];
        const float* wb = s_w + k4 * 256 + cg * 16;
        #pragma unroll
        for (int kk = 0; kk < 4; ++kk) {
            const float* wr = wb + kk * 64;
            #pragma unroll
            for (int i = 0; i < 4; ++i) {
                const float ga[4] = { gv[i].x, gv[i].y, gv[i].z, gv[i].w };
                const float gk = ga[kk];
                #pragma unroll
                for (int c = 0; c < 16; ++c)
                    acc[i][c] = fmaf(gk, wr[c], acc[i][c]);
            }
        }
        #pragma unroll
        for (int i = 0; i < 4; ++i) gv[i] = gvn[i];
    }

    // ---- part 2: gathered voxel rows @ w[64:128] ----
    #pragma unroll
    for (int i = 0; i < 4; ++i) gv[i] = vrow[i][0];
    for (int k4 = 0; k4 < 16; ++k4) {
        const int k4n = (k4 + 1) & 15;
        #pragma unroll
        for (int i = 0; i < 4; ++i) gvn[i] = vrow[i][k4n];
        const float* wb = s_w + 4096 + k4 * 256 + cg * 16;
        #pragma unroll
        for (int kk = 0; kk < 4; ++kk) {
            const float* wr = wb + kk * 64;
            #pragma unroll
            for (int i = 0; i < 4; ++i) {
                const float ga[4] = { gv[i].x, gv[i].y, gv[i].z, gv[i].w };
                const float gk = ga[kk];
                #pragma unroll
                for (int c = 0; c < 16; ++c)
                    acc[i][c] = fmaf(gk, wr[c], acc[i][c]);
            }
        }
        #pragma unroll
        for (int i = 0; i < 4; ++i) gv[i] = gvn[i];
    }

    // all reads of this block's p0 rows complete before in-place overwrite
    __syncthreads();

    #pragma unroll
    for (int i = 0; i < 4; ++i) {
        if (!ok[i]) continue;
        const float* xr = xyz + (size_t)p[i] * 3;
        const float* fr = pfeat + (size_t)p[i] * 61;
        float4* orow = reinterpret_cast<float4*>(io + (size_t)p[i] * 64 + cg * 16);
        #pragma unroll
        for (int q = 0; q < 4; ++q) {
            const int c = cg * 16 + q * 4;
            const float s0 = (c + 0 < 3) ? xr[c + 0] : fr[c - 3];
            const float s1 = (c + 1 < 3) ? xr[c + 1] : fr[c - 2];
            const float s2 = (c + 2 < 3) ? xr[c + 2] : fr[c - 1];
            const float s3 = (c + 3 < 3) ? xr[c + 3] : fr[c + 0];
            float4 u;
            u.x = fmaxf(acc[i][q * 4 + 0], 0.f) + s0;
            u.y = fmaxf(acc[i][q * 4 + 1], 0.f) + s1;
            u.z = fmaxf(acc[i][q * 4 + 2], 0.f) + s2;
            u.w = fmaxf(acc[i][q * 4 + 3], 0.f) + s3;
            orow[q] = u;
        }
    }
}

extern "C" void kernel_launch(void* const* d_in, const int* in_sizes, int n_in,
                              void* d_out, int out_size, void* d_ws, size_t ws_size,
                              hipStream_t stream) {
    const float* xyz   = (const float*)d_in[0];
    const float* pfeat = (const float*)d_in[1];
    const float* fclu  = (const float*)d_in[2];
    const int*   coors = (const int*)d_in[3];
    const float* rw0 = (const float*)d_in[4];
    const float* rg0 = (const float*)d_in[5];
    const float* rb0 = (const float*)d_in[6];
    const float* rw1 = (const float*)d_in[7];
    const float* rg1 = (const float*)d_in[8];
    const float* rb1 = (const float*)d_in[9];
    const float* vw0 = (const float*)d_in[10];
    const float* vg0 = (const float*)d_in[11];
    const float* vb0 = (const float*)d_in[12];
    const float* vw1 = (const float*)d_in[13];
    const float* vg1 = (const float*)d_in[14];
    const float* vb1 = (const float*)d_in[15];

    float*        out  = (float*)d_out;
    unsigned int* vmax = (unsigned int*)d_ws;
    const int npts = in_sizes[3];
    const int blocks = (npts + 255) / 256;

    // zero voxel-max buffer (identity for max over relu outputs; empty -> 0)
    hipMemsetAsync(d_ws, 0, (size_t)VVOX * 64 * sizeof(float), stream);

    hipLaunchKernelGGL(sir_k1a, dim3(blocks), dim3(256), 0, stream,
                       xyz, pfeat, fclu,
                       rw0, rg0, rb0, rw1, rg1, rb1,
                       out, npts);

    hipLaunchKernelGGL(sir_k1b, dim3(blocks), dim3(256), 0, stream,
                       out, coors, vw0, vg0, vb0, vmax, out, npts);

    hipLaunchKernelGGL(sir_k2, dim3(blocks), dim3(256), 0, stream,
                       xyz, pfeat, coors,
                       vw1, vg1, vb1, (const float*)d_ws, out, npts);
}